// Round 1
// baseline (336.412 us; speedup 1.0000x reference)
//
#include <hip/hip_runtime.h>
#include <cstddef>

#define B_   4
#define S_   1024
#define H_   400
#define NL_  16
#define NT_  65
#define EPSN (-1e-8f)
#define NEG_ (-1e9f)

// ---------------- kernel 1: projection + log-softmax + derived per-label ----
// 8 tokens per block, 256 threads. thread tid: tag t = tid>>2 (0..63),
// K-quarter q = tid&3 (100 elements each). Tag 64 handled by tid<4 in a
// second small pass. Then per-wave (64-lane) softmax for 2 tokens each.
__global__ __launch_bounds__(256) void k1_proj(
    const float* __restrict__ x, const float* __restrict__ W,
    const float* __restrict__ bias,
    float* __restrict__ inside, float* __restrict__ beginv,
    float* __restrict__ endv)
{
    __shared__ float xs[8 * H_];       // 12.8 KB
    __shared__ float lg[8 * NT_];      // 8 x 65 logits

    const int tid = threadIdx.x;
    const int tokBase = blockIdx.x * 8;

    // stage 8 x rows (8*400 floats = 800 float4, rows are 1600B -> 16B aligned)
    {
        const float4* x4 = (const float4*)(x + (size_t)tokBase * H_);
        float4* xs4 = (float4*)xs;
        for (int idx = tid; idx < 8 * H_ / 4; idx += 256) xs4[idx] = x4[idx];
    }
    __syncthreads();

    const int t = tid >> 2, q = tid & 3;
    float acc[8];
#pragma unroll
    for (int k = 0; k < 8; ++k) acc[k] = 0.f;
    const int k0 = q * 100;
    for (int k = k0; k < k0 + 100; ++k) {
        float w = W[k * NT_ + t];      // coalesced across tags, L2-resident
#pragma unroll
        for (int tok = 0; tok < 8; ++tok)
            acc[tok] = fmaf(xs[tok * H_ + k], w, acc[tok]);
    }
#pragma unroll
    for (int tok = 0; tok < 8; ++tok) {
        acc[tok] += __shfl_xor(acc[tok], 1);
        acc[tok] += __shfl_xor(acc[tok], 2);
    }
    if (q == 0) {
        float bt = bias[t];
#pragma unroll
        for (int tok = 0; tok < 8; ++tok) lg[tok * NT_ + t] = acc[tok] + bt;
    }
    // tag 64 on threads 0..3
    if (tid < 4) {
        float a64[8];
#pragma unroll
        for (int k = 0; k < 8; ++k) a64[k] = 0.f;
        const int kk0 = tid * 100;
        for (int k = kk0; k < kk0 + 100; ++k) {
            float w = W[k * NT_ + 64];
#pragma unroll
            for (int tok = 0; tok < 8; ++tok)
                a64[tok] = fmaf(xs[tok * H_ + k], w, a64[tok]);
        }
#pragma unroll
        for (int tok = 0; tok < 8; ++tok) {
            a64[tok] += __shfl_xor(a64[tok], 1);
            a64[tok] += __shfl_xor(a64[tok], 2);
        }
        if (tid == 0) {
            float b64 = bias[64];
#pragma unroll
            for (int tok = 0; tok < 8; ++tok) lg[tok * NT_ + 64] = a64[tok] + b64;
        }
    }
    __syncthreads();

    // softmax + derived. wave w handles tokens w and w+4.
    const int wave = tid >> 6, lane = tid & 63;
#pragma unroll
    for (int rep = 0; rep < 2; ++rep) {
        const int tok = wave + rep * 4;
        float v   = lg[tok * NT_ + lane];
        float v64 = lg[tok * NT_ + 64];
        float m = v;
#pragma unroll
        for (int d = 32; d; d >>= 1) m = fmaxf(m, __shfl_xor(m, d));
        m = fmaxf(m, v64);
        float e = __expf(v - m);
#pragma unroll
        for (int d = 32; d; d >>= 1) e += __shfl_xor(e, d);
        e += __expf(v64 - m);
        const float logden = m + __logf(e);

        if (lane < NL_) {
            const int l = lane;
            const float vI = lg[tok * NT_ + 1 + 4 * l] - logden;
            const float vB = lg[tok * NT_ + 2 + 4 * l] - logden;
            const float vL = lg[tok * NT_ + 3 + 4 * l] - logden;
            const float vU = lg[tok * NT_ + 4 + 4 * l] - logden;
            // logaddexp(B,U), logaddexp(L,U)
            float mb = fmaxf(vB, vU), nb = fminf(vB, vU);
            float bg = mb + log1pf(__expf(nb - mb));
            float me = fmaxf(vL, vU), ne = fminf(vL, vU);
            float en = me + log1pf(__expf(ne - me));
            // logsumexp of 4
            float mi = fmaxf(fmaxf(vI, vB), fmaxf(vL, vU));
            float si = __expf(vI - mi) + __expf(vB - mi) +
                       __expf(vL - mi) + __expf(vU - mi);
            float ins = mi + __logf(si);

            const int gtok = tokBase + tok;
            beginv[gtok * NL_ + l] = bg;
            endv  [gtok * NL_ + l] = en;
            inside[gtok * NL_ + l] = ins;
        }
    }
}

// ---------------- kernel 2: exclusive-padded cumsum over seq per (b,l) -----
__global__ __launch_bounds__(64) void k2_scan(
    const float* __restrict__ inside, float* __restrict__ cum)
{
    const int b = blockIdx.x >> 4, l = blockIdx.x & 15;
    const int lane = threadIdx.x;
    float p[16];
    float run = 0.f;
    const int s0 = lane * 16;
#pragma unroll
    for (int k = 0; k < 16; ++k) {
        run += inside[((b * S_) + s0 + k) * NL_ + l];
        p[k] = run;
    }
    const float tot = run;
    float sc = tot;
#pragma unroll
    for (int d = 1; d < 64; d <<= 1) {
        float o = __shfl_up(sc, d);
        if (lane >= d) sc += o;
    }
    const float excl = sc - tot;  // sum of all lanes < lane
    if (lane == 0) cum[(b * (S_ + 1)) * NL_ + l] = 0.f;
#pragma unroll
    for (int k = 0; k < 16; ++k)
        cum[((b * (S_ + 1)) + s0 + 1 + k) * NL_ + l] = excl + p[k];
}

// ---------------- kernel 3: the 256 MiB output fill ------------------------
// block: 256 threads = 64 j's x 4 float4 label-groups, fixed (b, i).
__global__ __launch_bounds__(256) void k3_fill(
    const float* __restrict__ cum, const float* __restrict__ beginv,
    const float* __restrict__ endv, float4* __restrict__ out)
{
    const int b = blockIdx.z, i = blockIdx.y;
    const int tid = threadIdx.x;
    const int l4 = tid & 3, jj = tid >> 2;
    const int j = blockIdx.x * 64 + jj;
    const size_t outIdx = (((size_t)(b * S_ + i)) * S_ + j) * 4 + l4;

    if (blockIdx.x * 64 + 63 < i) {   // whole block strictly below diagonal
        out[outIdx] = make_float4(NEG_, NEG_, NEG_, NEG_);
        return;
    }

    float4 r;
    if (i <= j) {
        const float4* cum4 = (const float4*)cum;
        const float4* bg4  = (const float4*)beginv;
        const float4* en4  = (const float4*)endv;
        float4 ci = cum4[(b * (S_ + 1) + i) * 4 + l4];
        float4 cj = cum4[(b * (S_ + 1) + j + 1) * 4 + l4];
        float4 bg = bg4[(b * S_ + i) * 4 + l4];
        float4 en = en4[(b * S_ + j) * 4 + l4];
        r.x = fminf(fminf(fminf(cj.x - ci.x, EPSN), bg.x), en.x);
        r.y = fminf(fminf(fminf(cj.y - ci.y, EPSN), bg.y), en.y);
        r.z = fminf(fminf(fminf(cj.z - ci.z, EPSN), bg.z), en.z);
        r.w = fminf(fminf(fminf(cj.w - ci.w, EPSN), bg.w), en.w);
    } else {
        r = make_float4(NEG_, NEG_, NEG_, NEG_);
    }
    out[outIdx] = r;
}

extern "C" void kernel_launch(void* const* d_in, const int* in_sizes, int n_in,
                              void* d_out, int out_size, void* d_ws, size_t ws_size,
                              hipStream_t stream) {
    const float* x    = (const float*)d_in[0];
    // d_in[1] = mask (unused; all-true in this problem)
    const float* W    = (const float*)d_in[2];
    const float* bias = (const float*)d_in[3];
    float* out = (float*)d_out;

    // workspace layout (all 16B aligned)
    char* ws = (char*)d_ws;
    float* inside = (float*)(ws);                       // 4*1024*16 f32 = 256 KB
    float* beginv = (float*)(ws + 262144);              // 256 KB
    float* endv   = (float*)(ws + 524288);              // 256 KB
    float* cum    = (float*)(ws + 786432);              // 4*1025*16 f32 ~ 256 KB

    k1_proj<<<dim3(B_ * S_ / 8), dim3(256), 0, stream>>>(x, W, bias,
                                                         inside, beginv, endv);
    k2_scan<<<dim3(B_ * NL_), dim3(64), 0, stream>>>(inside, cum);
    k3_fill<<<dim3(S_ / 64, S_, B_), dim3(256), 0, stream>>>(
        cum, beginv, endv, (float4*)out);
}

// Round 3
// 309.441 us; speedup vs baseline: 1.0872x; 1.0872x over previous
//
#include <hip/hip_runtime.h>
#include <cstddef>

#define B_   4
#define S_   1024
#define H_   400
#define NL_  16
#define NT_  65
#define EPSN (-1e-8f)
#define NEG_ (-1e9f)

typedef float f32x4 __attribute__((ext_vector_type(4)));

// ---------------- kernel 1: projection + log-softmax + derived per-label ----
// 256 blocks x 256 threads (4 waves). 16 tokens/block, 4 tokens per wave
// processed simultaneously in the k-loop. W staged in LDS: per k-iter each
// lane reads WL[k*65+1+lane] (lane = tag-1, 2-way bank alias = free) plus a
// broadcast w0; x rows staged in LDS, broadcast reads. Softmax fully in-wave.
__global__ __launch_bounds__(256) void k1_proj(
    const float* __restrict__ x, const float* __restrict__ W,
    const float* __restrict__ bias,
    float* __restrict__ inside_t,   // [b*16+l][1024]  (transposed for k2)
    float* __restrict__ beginv,     // [b*1024+s][16]
    float* __restrict__ endv)       // [b*1024+s][16]
{
    __shared__ float WL[H_ * NT_];   // 104,000 B
    __shared__ float xs[16 * H_];    //  25,600 B   (total 129.6 KB < 160 KB)

    const int tid = threadIdx.x;
    const int tokBase = blockIdx.x * 16;

    // stage W (26000 floats = 6500 float4) and 16 x-rows (6400 floats)
    {
        const f32x4* W4 = (const f32x4*)W;
        f32x4* WL4 = (f32x4*)WL;
        for (int i = tid; i < H_ * NT_ / 4; i += 256) WL4[i] = W4[i];
        const f32x4* x4 = (const f32x4*)(x + (size_t)tokBase * H_);
        f32x4* xs4 = (f32x4*)xs;
        for (int i = tid; i < 16 * H_ / 4; i += 256) xs4[i] = x4[i];
    }
    __syncthreads();

    const int wave = tid >> 6, lane = tid & 63;

    float acc[4], acc0[4];
#pragma unroll
    for (int r = 0; r < 4; ++r) { acc[r] = 0.f; acc0[r] = 0.f; }

#pragma unroll 4
    for (int k = 0; k < H_; ++k) {
        const float wt = WL[k * NT_ + 1 + lane];   // lane -> tag 1..64
        const float w0 = WL[k * NT_];              // tag 0, broadcast
#pragma unroll
        for (int r = 0; r < 4; ++r) {
            const float xv = xs[(wave * 4 + r) * H_ + k];  // broadcast
            acc[r]  = fmaf(xv, wt, acc[r]);
            acc0[r] = fmaf(xv, w0, acc0[r]);
        }
    }

    const float bt = bias[1 + lane];
    const float b0 = bias[0];
    const int g = lane & ~3;          // 4-lane group base (label)
    const int L = lane >> 2, kind = lane & 3;

#pragma unroll
    for (int r = 0; r < 4; ++r) {
        const float lt = acc[r] + bt;
        const float l0 = acc0[r] + b0;
        // softmax denominator over 65 tags
        float m = lt;
#pragma unroll
        for (int d = 32; d; d >>= 1) m = fmaxf(m, __shfl_xor(m, d));
        m = fmaxf(m, l0);
        float e = __expf(lt - m);
#pragma unroll
        for (int d = 32; d; d >>= 1) e += __shfl_xor(e, d);
        e += __expf(l0 - m);
        const float logden = m + __logf(e);
        const float lm = lt - logden;   // log-marginal of tag lane+1

        // gather the 4 kinds of this label: I,B,L,U = kinds 0..3
        const float vI = __shfl(lm, g + 0);
        const float vB = __shfl(lm, g + 1);
        const float vL = __shfl(lm, g + 2);
        const float vU = __shfl(lm, g + 3);

        float mb = fmaxf(vB, vU), nb = fminf(vB, vU);
        const float bg = mb + log1pf(__expf(nb - mb));
        float me = fmaxf(vL, vU), ne = fminf(vL, vU);
        const float en = me + log1pf(__expf(ne - me));
        float mi = fmaxf(fmaxf(vI, vB), fmaxf(vL, vU));
        const float ins = mi + __logf(__expf(vI - mi) + __expf(vB - mi) +
                                      __expf(vL - mi) + __expf(vU - mi));

        const int gtok = tokBase + wave * 4 + r;
        const int b = gtok >> 10, s = gtok & 1023;
        if (kind == 0) inside_t[(b * NL_ + L) * S_ + s] = ins;
        if (kind == 1) beginv[gtok * NL_ + L] = bg;
        if (kind == 2) endv[gtok * NL_ + L] = en;
    }
}

// ---------------- kernel 2: exclusive-padded cumsum over seq per (b,l) -----
// one wave per (b,l); contiguous float4 loads from inside_t.
__global__ __launch_bounds__(64) void k2_scan(
    const float* __restrict__ inside_t, float* __restrict__ cum)
{
    const int bl = blockIdx.x;        // b*16 + l
    const int b = bl >> 4, l = bl & 15;
    const int lane = threadIdx.x;
    const int s0 = lane * 16;

    const f32x4* src = (const f32x4*)(inside_t + bl * S_ + s0);
    float v[16];
#pragma unroll
    for (int q = 0; q < 4; ++q) {
        f32x4 t = src[q];
        v[q * 4 + 0] = t.x; v[q * 4 + 1] = t.y;
        v[q * 4 + 2] = t.z; v[q * 4 + 3] = t.w;
    }
    float run = 0.f;
    float p[16];
#pragma unroll
    for (int k = 0; k < 16; ++k) { run += v[k]; p[k] = run; }
    const float tot = run;
    float sc = tot;
#pragma unroll
    for (int d = 1; d < 64; d <<= 1) {
        float o = __shfl_up(sc, d);
        if (lane >= d) sc += o;
    }
    const float excl = sc - tot;      // sum over lanes < lane
    if (lane == 0) cum[(b * (S_ + 1)) * NL_ + l] = 0.f;
#pragma unroll
    for (int k = 0; k < 16; ++k)
        cum[((b * (S_ + 1)) + s0 + 1 + k) * NL_ + l] = excl + p[k];
}

// ---------------- kernel 3: the 256 MiB output fill ------------------------
// block: 256 threads, fixed (b,i), 256 j's; thread (jj,l4) writes 4 float4
// along j (each wave-store = 1 KB contiguous). Nontemporal stores.
__global__ __launch_bounds__(256) void k3_fill(
    const float* __restrict__ cum, const float* __restrict__ beginv,
    const float* __restrict__ endv, f32x4* __restrict__ out)
{
    const int b = blockIdx.z, i = blockIdx.y;
    const int tid = threadIdx.x;
    const int l4 = tid & 3, jj = tid >> 2;
    const int jbase = blockIdx.x * 256;
    const size_t rowBase = ((size_t)(b * S_ + i) * S_) * 4 + l4;

    const f32x4 neg = { NEG_, NEG_, NEG_, NEG_ };

    if (jbase + 255 < i) {            // whole block strictly below diagonal
#pragma unroll
        for (int jr = 0; jr < 4; ++jr) {
            const int j = jbase + jr * 64 + jj;
            __builtin_nontemporal_store(neg, &out[rowBase + (size_t)j * 4]);
        }
        return;
    }

    const f32x4* cum4 = (const f32x4*)cum;
    const f32x4* bg4  = (const f32x4*)beginv;
    const f32x4* en4  = (const f32x4*)endv;
    const f32x4 ci = cum4[(b * (S_ + 1) + i) * 4 + l4];
    const f32x4 bg = bg4[(b * S_ + i) * 4 + l4];

#pragma unroll
    for (int jr = 0; jr < 4; ++jr) {
        const int j = jbase + jr * 64 + jj;
        f32x4 r;
        if (i <= j) {
            const f32x4 cj = cum4[(b * (S_ + 1) + j + 1) * 4 + l4];
            const f32x4 en = en4[(b * S_ + j) * 4 + l4];
            r.x = fminf(fminf(fminf(cj.x - ci.x, EPSN), bg.x), en.x);
            r.y = fminf(fminf(fminf(cj.y - ci.y, EPSN), bg.y), en.y);
            r.z = fminf(fminf(fminf(cj.z - ci.z, EPSN), bg.z), en.z);
            r.w = fminf(fminf(fminf(cj.w - ci.w, EPSN), bg.w), en.w);
        } else {
            r = neg;
        }
        __builtin_nontemporal_store(r, &out[rowBase + (size_t)j * 4]);
    }
}

extern "C" void kernel_launch(void* const* d_in, const int* in_sizes, int n_in,
                              void* d_out, int out_size, void* d_ws, size_t ws_size,
                              hipStream_t stream) {
    const float* x    = (const float*)d_in[0];
    // d_in[1] = mask (all-true in this problem; unused)
    const float* W    = (const float*)d_in[2];
    const float* bias = (const float*)d_in[3];

    char* ws = (char*)d_ws;
    float* inside_t = (float*)(ws);            // [64][1024]   = 256 KB
    float* beginv   = (float*)(ws + 262144);   // [4096][16]   = 256 KB
    float* endv     = (float*)(ws + 524288);   // [4096][16]   = 256 KB
    float* cum      = (float*)(ws + 786432);   // [4][1025][16] ~ 256 KB

    k1_proj<<<dim3(B_ * S_ / 16), dim3(256), 0, stream>>>(x, W, bias,
                                                          inside_t, beginv, endv);
    k2_scan<<<dim3(B_ * NL_), dim3(64), 0, stream>>>(inside_t, cum);
    k3_fill<<<dim3(S_ / 256, S_, B_), dim3(256), 0, stream>>>(
        cum, beginv, endv, (f32x4*)d_out);
}

// Round 4
// 305.079 us; speedup vs baseline: 1.1027x; 1.0143x over previous
//
#include <hip/hip_runtime.h>
#include <cstddef>

#define B_   4
#define S_   1024
#define H_   400
#define NL_  16
#define NT_  65
#define KP_  404          // padded k-stride for transposed W in LDS
#define EPSN (-1e-8f)
#define NEG_ (-1e9f)

typedef float f32x4 __attribute__((ext_vector_type(4)));

// ---------------- kernel 1: projection + log-softmax + derived per-label ----
// 256 blocks x 256 threads (4 waves), 16 tokens/block, 4 tokens/wave.
// W staged TRANSPOSED in LDS as WLt[tag][k] with k-stride 404 so that the
// lane-indexed ds_read_b128 (lane -> tag 1..64, 4 k's at once) is
// bank-conflict-free: (404*lane) mod 32 walks 8 distinct 16B chunks covering
// all 32 banks per 8 lanes. x rows read as broadcast b128. 6 b128 reads feed
// 32 FMAs per k-tile (vs 24 b32 reads in the previous version).
__global__ __launch_bounds__(256) void k1_proj(
    const float* __restrict__ x, const float* __restrict__ W,
    const float* __restrict__ bias,
    float* __restrict__ inside_t,   // [b*16+l][1024]  (transposed for k2)
    float* __restrict__ beginv,     // [b*1024+s][16]
    float* __restrict__ endv)       // [b*1024+s][16]
{
    __shared__ float WLt[NT_ * KP_];   // 65*404*4 = 105,040 B
    __shared__ float xs[16 * H_];      // 25,600 B  (total ~130.6 KB)

    const int tid = threadIdx.x;
    const int tokBase = blockIdx.x * 16;

    // stage W transposed: global [k][t] row-major -> LDS [t][k] (stride KP_)
    {
        const f32x4* W4 = (const f32x4*)W;
        for (int i4 = tid; i4 < H_ * NT_ / 4; i4 += 256) {
            f32x4 v = W4[i4];
            const int base = i4 * 4;
#pragma unroll
            for (int c = 0; c < 4; ++c) {
                const int idx = base + c;
                const int k = idx / NT_;
                const int t = idx - k * NT_;
                WLt[t * KP_ + k] = v[c];
            }
        }
        const f32x4* x4 = (const f32x4*)(x + (size_t)tokBase * H_);
        f32x4* xs4 = (f32x4*)xs;
        for (int i = tid; i < 16 * H_ / 4; i += 256) xs4[i] = x4[i];
    }
    __syncthreads();

    const int wave = tid >> 6, lane = tid & 63;

    float acc[4], acc0[4];
#pragma unroll
    for (int r = 0; r < 4; ++r) { acc[r] = 0.f; acc0[r] = 0.f; }

    const f32x4* wt4p = (const f32x4*)&WLt[(1 + lane) * KP_];
    const f32x4* w04p = (const f32x4*)&WLt[0];

#pragma unroll 2
    for (int kt = 0; kt < H_ / 4; ++kt) {
        const f32x4 wt = wt4p[kt];     // lane -> tag 1..64, conflict-free b128
        const f32x4 w0 = w04p[kt];     // tag 0, broadcast b128
#pragma unroll
        for (int r = 0; r < 4; ++r) {
            const f32x4 xv = ((const f32x4*)&xs[(wave * 4 + r) * H_])[kt];
            acc[r]  = fmaf(xv.x, wt.x, acc[r]);
            acc[r]  = fmaf(xv.y, wt.y, acc[r]);
            acc[r]  = fmaf(xv.z, wt.z, acc[r]);
            acc[r]  = fmaf(xv.w, wt.w, acc[r]);
            acc0[r] = fmaf(xv.x, w0.x, acc0[r]);
            acc0[r] = fmaf(xv.y, w0.y, acc0[r]);
            acc0[r] = fmaf(xv.z, w0.z, acc0[r]);
            acc0[r] = fmaf(xv.w, w0.w, acc0[r]);
        }
    }

    const float bt = bias[1 + lane];
    const float b0 = bias[0];
    const int g = lane & ~3;          // 4-lane group base (label)
    const int L = lane >> 2, kind = lane & 3;

#pragma unroll
    for (int r = 0; r < 4; ++r) {
        const float lt = acc[r] + bt;
        const float l0 = acc0[r] + b0;
        // softmax denominator over 65 tags
        float m = lt;
#pragma unroll
        for (int d = 32; d; d >>= 1) m = fmaxf(m, __shfl_xor(m, d));
        m = fmaxf(m, l0);
        float e = __expf(lt - m);
#pragma unroll
        for (int d = 32; d; d >>= 1) e += __shfl_xor(e, d);
        e += __expf(l0 - m);
        const float logden = m + __logf(e);
        const float lm = lt - logden;   // log-marginal of tag lane+1

        // gather the 4 kinds of this label: I,B,L,U = kinds 0..3
        const float vI = __shfl(lm, g + 0);
        const float vB = __shfl(lm, g + 1);
        const float vL = __shfl(lm, g + 2);
        const float vU = __shfl(lm, g + 3);

        float mb = fmaxf(vB, vU), nb = fminf(vB, vU);
        const float bg = mb + log1pf(__expf(nb - mb));
        float me = fmaxf(vL, vU), ne = fminf(vL, vU);
        const float en = me + log1pf(__expf(ne - me));
        float mi = fmaxf(fmaxf(vI, vB), fmaxf(vL, vU));
        const float ins = mi + __logf(__expf(vI - mi) + __expf(vB - mi) +
                                      __expf(vL - mi) + __expf(vU - mi));

        const int gtok = tokBase + wave * 4 + r;
        const int b = gtok >> 10, s = gtok & 1023;
        if (kind == 0) inside_t[(b * NL_ + L) * S_ + s] = ins;
        if (kind == 1) beginv[gtok * NL_ + L] = bg;
        if (kind == 2) endv[gtok * NL_ + L] = en;
    }
}

// ---------------- kernel 2: exclusive-padded cumsum over seq per (b,l) -----
// one wave per (b,l); contiguous float4 loads from inside_t.
__global__ __launch_bounds__(64) void k2_scan(
    const float* __restrict__ inside_t, float* __restrict__ cum)
{
    const int bl = blockIdx.x;        // b*16 + l
    const int b = bl >> 4, l = bl & 15;
    const int lane = threadIdx.x;
    const int s0 = lane * 16;

    const f32x4* src = (const f32x4*)(inside_t + bl * S_ + s0);
    float v[16];
#pragma unroll
    for (int q = 0; q < 4; ++q) {
        f32x4 t = src[q];
        v[q * 4 + 0] = t.x; v[q * 4 + 1] = t.y;
        v[q * 4 + 2] = t.z; v[q * 4 + 3] = t.w;
    }
    float run = 0.f;
    float p[16];
#pragma unroll
    for (int k = 0; k < 16; ++k) { run += v[k]; p[k] = run; }
    const float tot = run;
    float sc = tot;
#pragma unroll
    for (int d = 1; d < 64; d <<= 1) {
        float o = __shfl_up(sc, d);
        if (lane >= d) sc += o;
    }
    const float excl = sc - tot;      // sum over lanes < lane
    if (lane == 0) cum[(b * (S_ + 1)) * NL_ + l] = 0.f;
#pragma unroll
    for (int k = 0; k < 16; ++k)
        cum[((b * (S_ + 1)) + s0 + 1 + k) * NL_ + l] = excl + p[k];
}

// ---------------- kernel 3: the 256 MiB output fill ------------------------
// block: 256 threads, fixed (b,i), 256 j's; thread (jj,l4) writes 4 float4
// along j (each wave-store = 1 KB contiguous). Nontemporal stores.
__global__ __launch_bounds__(256) void k3_fill(
    const float* __restrict__ cum, const float* __restrict__ beginv,
    const float* __restrict__ endv, f32x4* __restrict__ out)
{
    const int b = blockIdx.z, i = blockIdx.y;
    const int tid = threadIdx.x;
    const int l4 = tid & 3, jj = tid >> 2;
    const int jbase = blockIdx.x * 256;
    const size_t rowBase = ((size_t)(b * S_ + i) * S_) * 4 + l4;

    const f32x4 neg = { NEG_, NEG_, NEG_, NEG_ };

    if (jbase + 255 < i) {            // whole block strictly below diagonal
#pragma unroll
        for (int jr = 0; jr < 4; ++jr) {
            const int j = jbase + jr * 64 + jj;
            __builtin_nontemporal_store(neg, &out[rowBase + (size_t)j * 4]);
        }
        return;
    }

    const f32x4* cum4 = (const f32x4*)cum;
    const f32x4* bg4  = (const f32x4*)beginv;
    const f32x4* en4  = (const f32x4*)endv;
    const f32x4 ci = cum4[(b * (S_ + 1) + i) * 4 + l4];
    const f32x4 bg = bg4[(b * S_ + i) * 4 + l4];

#pragma unroll
    for (int jr = 0; jr < 4; ++jr) {
        const int j = jbase + jr * 64 + jj;
        f32x4 r;
        if (i <= j) {
            const f32x4 cj = cum4[(b * (S_ + 1) + j + 1) * 4 + l4];
            const f32x4 en = en4[(b * S_ + j) * 4 + l4];
            r.x = fminf(fminf(fminf(cj.x - ci.x, EPSN), bg.x), en.x);
            r.y = fminf(fminf(fminf(cj.y - ci.y, EPSN), bg.y), en.y);
            r.z = fminf(fminf(fminf(cj.z - ci.z, EPSN), bg.z), en.z);
            r.w = fminf(fminf(fminf(cj.w - ci.w, EPSN), bg.w), en.w);
        } else {
            r = neg;
        }
        __builtin_nontemporal_store(r, &out[rowBase + (size_t)j * 4]);
    }
}

extern "C" void kernel_launch(void* const* d_in, const int* in_sizes, int n_in,
                              void* d_out, int out_size, void* d_ws, size_t ws_size,
                              hipStream_t stream) {
    const float* x    = (const float*)d_in[0];
    // d_in[1] = mask (all-true in this problem; unused)
    const float* W    = (const float*)d_in[2];
    const float* bias = (const float*)d_in[3];

    char* ws = (char*)d_ws;
    float* inside_t = (float*)(ws);            // [64][1024]   = 256 KB
    float* beginv   = (float*)(ws + 262144);   // [4096][16]   = 256 KB
    float* endv     = (float*)(ws + 524288);   // [4096][16]   = 256 KB
    float* cum      = (float*)(ws + 786432);   // [4][1025][16] ~ 256 KB

    k1_proj<<<dim3(B_ * S_ / 16), dim3(256), 0, stream>>>(x, W, bias,
                                                          inside_t, beginv, endv);
    k2_scan<<<dim3(B_ * NL_), dim3(64), 0, stream>>>(inside_t, cum);
    k3_fill<<<dim3(S_ / 256, S_, B_), dim3(256), 0, stream>>>(
        cum, beginv, endv, (f32x4*)d_out);
}